// Round 20
// baseline (507.180 us; speedup 1.0000x reference)
//
#include <hip/hip_runtime.h>
#include <hip/hip_bf16.h>
#include <cstddef>

typedef short bf16x8 __attribute__((ext_vector_type(8)));
typedef float f32x4 __attribute__((ext_vector_type(4)));

__device__ __forceinline__ unsigned short f2bf(float x) {
  __hip_bfloat16 h = __float2bfloat16(x);
  unsigned short u; __builtin_memcpy(&u, &h, 2); return u;
}
__device__ __forceinline__ float bf2f(unsigned short u) {
  unsigned int v = ((unsigned int)u) << 16; float f; __builtin_memcpy(&f, &v, 4); return f;
}
__device__ __forceinline__ float swz16f(float x) {   // lane ^= 16 (within 32-group)
  int i; __builtin_memcpy(&i, &x, 4);
  i = __builtin_amdgcn_ds_swizzle(i, 0x401F);
  float r; __builtin_memcpy(&r, &i, 4); return r;
}
__device__ __forceinline__ void gload16(const unsigned short* g, unsigned short* l) {
  __builtin_amdgcn_global_load_lds(
      (const __attribute__((address_space(1))) void*)g,
      (__attribute__((address_space(3))) void*)l, 16, 0, 0);
}
__device__ __forceinline__ void pipe_sync() {
  asm volatile("s_waitcnt vmcnt(0)" ::: "memory");
  __builtin_amdgcn_s_barrier();
  __builtin_amdgcn_sched_barrier(0);
}
__device__ __forceinline__ void bar_only() {
  asm volatile("" ::: "memory");
  __builtin_amdgcn_s_barrier();
  __builtin_amdgcn_sched_barrier(0);
}

// ---------------- all weights fp32 -> bf16 (contiguous dst) ----------------
__global__ __launch_bounds__(256) void cvt_all(
    const float* __restrict__ qkv_w, const float* __restrict__ out_w,
    const float* __restrict__ fc1_w, const float* __restrict__ fc2_w,
    const float* __restrict__ outp_w, unsigned short* __restrict__ dst)
{
  int i = blockIdx.x * 256 + threadIdx.x;
  if (i >= 1576960) return;
  const float* src; int off;
  if (i < 786432)       { src = qkv_w;  off = i; }
  else if (i < 1048576) { src = out_w;  off = i - 786432; }
  else if (i < 1310720) { src = fc1_w;  off = i - 1048576; }
  else if (i < 1572864) { src = fc2_w;  off = i - 1310720; }
  else                  { src = outp_w; off = i - 1572864; }
  float4 v = *(const float4*)(src + (size_t)off * 4);
  ushort4 o;
  o.x = f2bf(v.x); o.y = f2bf(v.y); o.z = f2bf(v.z); o.w = f2bf(v.w);
  *(ushort4*)(dst + (size_t)i * 4) = o;
}

// ---------------- conv1d (circular, k=3) + positional embedding -> bf16 ------
__global__ __launch_bounds__(256) void conv_pe_kernel(
    const float* __restrict__ x, const float* __restrict__ cw,
    const float* __restrict__ cb, unsigned short* __restrict__ outb)
{
  const int L = 2048;
  int b  = blockIdx.x >> 8;
  int l0 = (blockIdx.x & 255) << 3;
  int t  = threadIdx.x;
  __shared__ __align__(16) float xs[10][32];
  for (int idx = t; idx < 320; idx += 256) {
    int rr = idx >> 5, ci = idx & 31;
    int gl = (l0 - 1 + rr + L) & (L - 1);
    xs[rr][ci] = x[((size_t)b * L + gl) * 32 + ci];
  }
  __syncthreads();
  int e0 = t << 1;
  float acc0[8], acc1[8];
  float bb0 = cb[e0], bb1 = cb[e0 + 1];
#pragma unroll
  for (int li = 0; li < 8; li++) { acc0[li] = bb0; acc1[li] = bb1; }

  const float4* w04 = (const float4*)(cw + (size_t)e0 * 96);
  const float4* w14 = (const float4*)(cw + (size_t)e0 * 96 + 96);

#pragma unroll
  for (int c4 = 0; c4 < 8; c4++) {
    float4 wa0 = w04[3 * c4], wa1 = w04[3 * c4 + 1], wa2 = w04[3 * c4 + 2];
    float4 wb0 = w14[3 * c4], wb1 = w14[3 * c4 + 1], wb2 = w14[3 * c4 + 2];
    float w0v[12] = {wa0.x, wa0.y, wa0.z, wa0.w, wa1.x, wa1.y, wa1.z, wa1.w,
                     wa2.x, wa2.y, wa2.z, wa2.w};
    float w1v[12] = {wb0.x, wb0.y, wb0.z, wb0.w, wb1.x, wb1.y, wb1.z, wb1.w,
                     wb2.x, wb2.y, wb2.z, wb2.w};
    float4 xr[10];
#pragma unroll
    for (int r = 0; r < 10; r++) xr[r] = *(const float4*)&xs[r][c4 * 4];
#pragma unroll
    for (int li = 0; li < 8; li++) {
#pragma unroll
      for (int kk = 0; kk < 3; kk++) {
        float4 xv = xr[li + kk];
        acc0[li] += xv.x * w0v[kk] + xv.y * w0v[3 + kk]
                  + xv.z * w0v[6 + kk] + xv.w * w0v[9 + kk];
        acc1[li] += xv.x * w1v[kk] + xv.y * w1v[3 + kk]
                  + xv.z * w1v[6 + kk] + xv.w * w1v[9 + kk];
      }
    }
  }

  float dv = __expf((float)e0 * (-9.210340371976184f / 512.0f));
#pragma unroll
  for (int li = 0; li < 8; li++) {
    int l = l0 + li;
    float arg = (float)l * dv;
    float sv = __sinf(arg), cv = __cosf(arg);
    size_t off = ((size_t)b * L + l) * 512 + e0;
    ushort2 ob; ob.x = f2bf(acc0[li] + sv); ob.y = f2bf(acc1[li] + cv);
    *(ushort2*)&outb[off] = ob;
  }
}

// ---------------- bf16 MFMA GEMM, 2-phase pipelined, counted vmcnt (T4) ------
template<int EPI, int QSCALE, int NFR, int VOUT>
__global__ __launch_bounds__(256) void gemm_bf(
    const unsigned short* __restrict__ X,
    const unsigned short* __restrict__ W,
    const float* __restrict__ bias,
    const unsigned short* __restrict__ R,
    unsigned short* __restrict__ Yb,
    float* __restrict__ Yf,
    unsigned short* __restrict__ VT,
    int N)
{
  const int K = 512;
  constexpr int BN = NFR * 32;
  constexpr int WB = NFR * 4096;
  constexpr int BUF = 16384 + WB;
  __shared__ __align__(16) char smem[2 * BUF];
  int t = threadIdx.x;
  int lane = t & 63, wv = t >> 6;
  int g = lane >> 4, li = lane & 15;
  int m0 = (blockIdx.x & 63) << 7;
  int n0 = (blockIdx.x >> 6) * BN;
  int wm = (wv >> 1) << 6;
  int wn = (wv & 1) * (BN / 2);

  int subrow = lane >> 3;
  int coloff = ((lane & 7) ^ subrow) << 3;

  f32x4 acc[4][NFR];
#pragma unroll
  for (int a = 0; a < 4; a++)
#pragma unroll
    for (int b2 = 0; b2 < NFR; b2++) acc[a][b2] = (f32x4){0.f, 0.f, 0.f, 0.f};

#pragma unroll
  for (int j = 0; j < 4; j++) {
    int row = (wv * 4 + j) * 8 + subrow;
    gload16(X + (size_t)(m0 + row) * K + coloff,
            (unsigned short*)(smem + (wv * 4 + j) * 1024));
  }
#pragma unroll
  for (int j = 0; j < NFR; j++) {
    int row = (wv * NFR + j) * 8 + subrow;
    gload16(W + (size_t)(n0 + row) * K + coloff,
            (unsigned short*)(smem + 16384 + (wv * NFR + j) * 1024));
  }

#pragma unroll
  for (int ks = 0; ks < 8; ks++) {
    const int buf = ks & 1;
    char* cur = smem + buf * BUF;
    if (ks < 7) {
      char* nxt = smem + (buf ^ 1) * BUF;
      int k0 = (ks + 1) * 64;
#pragma unroll
      for (int j = 0; j < 4; j++) {
        int row = (wv * 4 + j) * 8 + subrow;
        gload16(X + (size_t)(m0 + row) * K + k0 + coloff,
                (unsigned short*)(nxt + (wv * 4 + j) * 1024));
      }
#pragma unroll
      for (int j = 0; j < NFR; j++) {
        int row = (wv * NFR + j) * 8 + subrow;
        gload16(W + (size_t)(n0 + row) * K + k0 + coloff,
                (unsigned short*)(nxt + 16384 + (wv * NFR + j) * 1024));
      }
      if constexpr (NFR == 4) asm volatile("s_waitcnt vmcnt(8)" ::: "memory");
      else if constexpr (NFR == 2) asm volatile("s_waitcnt vmcnt(6)" ::: "memory");
      else asm volatile("s_waitcnt vmcnt(5)" ::: "memory");
    } else {
      asm volatile("s_waitcnt vmcnt(0)" ::: "memory");
    }
    __builtin_amdgcn_s_barrier();
    __builtin_amdgcn_sched_barrier(0);

#pragma unroll
    for (int s = 0; s < 2; s++) {
      bf16x8 af[4], bfr[NFR];
#pragma unroll
      for (int mt = 0; mt < 4; mt++) {
        int row = wm + 16 * mt + li;
        af[mt] = *(const bf16x8*)(cur + (row * 8 + ((g + 4 * s) ^ (row & 7))) * 16);
      }
#pragma unroll
      for (int nt = 0; nt < NFR; nt++) {
        int row = wn + 16 * nt + li;
        bfr[nt] = *(const bf16x8*)(cur + 16384 +
                                   (row * 8 + ((g + 4 * s) ^ (row & 7))) * 16);
      }
#pragma unroll
      for (int mt = 0; mt < 4; mt++)
#pragma unroll
        for (int nt = 0; nt < NFR; nt++)
          acc[mt][nt] = __builtin_amdgcn_mfma_f32_16x16x32_bf16(
              af[mt], bfr[nt], acc[mt][nt], 0, 0, 0);
    }
    if (ks < 7) bar_only();
  }

  float bv[NFR];
#pragma unroll
  for (int nt = 0; nt < NFR; nt++) bv[nt] = bias[n0 + wn + 16 * nt + li];

  if (VOUT && n0 >= 1024) {
    unsigned short* Ts = (unsigned short*)smem;
    __builtin_amdgcn_s_barrier();
#pragma unroll
    for (int nt = 0; nt < NFR; nt++) {
      int col = wn + 16 * nt + li;
      float bvn = bv[nt];
#pragma unroll
      for (int mt = 0; mt < 4; mt++) {
        float v0 = acc[mt][nt][0] + bvn, v1 = acc[mt][nt][1] + bvn;
        float v2 = acc[mt][nt][2] + bvn, v3 = acc[mt][nt][3] + bvn;
        uint2 pk;
        asm("v_cvt_pk_bf16_f32 %0, %1, %2" : "=v"(pk.x) : "v"(v0), "v"(v1));
        asm("v_cvt_pk_bf16_f32 %0, %1, %2" : "=v"(pk.y) : "v"(v2), "v"(v3));
        *(uint2*)(Ts + col * 136 + wm + 16 * mt + 4 * g) = pk;
      }
    }
    __syncthreads();
    int vcol = t >> 1, half = t & 1;
    int gc = n0 - 1024 + vcol;
    int bh = (m0 >> 11) * 8 + (gc >> 6);
    int d  = gc & 63;
    unsigned short* dst = VT + ((size_t)bh * 64 + d) * 2048 + (m0 & 2047) + half * 64;
    const unsigned short* srcp = Ts + vcol * 136 + half * 64;
#pragma unroll
    for (int j2 = 0; j2 < 8; j2++)
      *(bf16x8*)(dst + j2 * 8) = *(const bf16x8*)(srcp + j2 * 8);
    return;
  }

#pragma unroll
  for (int mt = 0; mt < 4; mt++) {
#pragma unroll
    for (int i = 0; i < 4; i++) {
      size_t roff = (size_t)(m0 + wm + 16 * mt + 4 * g + i) * N;
#pragma unroll
      for (int nt = 0; nt < NFR; nt++) {
        int col = n0 + wn + 16 * nt + li;
        float v = acc[mt][nt][i] + bv[nt];
        if (EPI == 1) {
          v += bf2f(R[roff + col]);
          Yb[roff + col] = f2bf(v);
        } else if (EPI == 2) {
          v = v / (1.f + __expf(-v));
          Yb[roff + col] = f2bf(v);
        } else if (EPI == 3) {
          Yf[roff + col] = v;
        } else {
          if (QSCALE && col < 512) v *= 0.18033688011112042f;  // 0.125*log2(e)
          Yb[roff + col] = f2bf(v);
        }
      }
    }
  }
}

// ---------------- MFMA flash attention, SPLIT-K=2, KVBLK=64 ----------------
// grid 1024: bh = bid&31 (XCD-local), qi = (bid>>5)&15, half = bid>>9.
// LDS 32KB -> 4 blocks/CU. NO-MAX softmax => unnormalized partials O,l ADD.
// r19 post-mortem: l is per (q,HEAD) — Lp was indexed by q only, so all 8
// heads raced on one slot and combine normalized every head by the race
// winner's l (~5% error). Lp is now [2][8][8192].
__global__ __launch_bounds__(256) void attn_mfma(
    const unsigned short* __restrict__ qkv,  // [8192,1536] bf16
    const unsigned short* __restrict__ Vt,   // [32,64,2048] bf16
    float* __restrict__ Op,                  // [2][8192][512] f32 partial O
    float* __restrict__ Lp)                  // [2][8][8192] f32 partial l
{
  const int L = 2048;
  int bh = blockIdx.x & 31;
  int rest = blockIdx.x >> 5;
  int qi = rest & 15, half = rest >> 4;
  int b = bh >> 3, h = bh & 7;
  int q0 = qi << 7;
  int kt0 = half << 10;
  size_t tb = (size_t)b * L;
  int t = threadIdx.x, lane = t & 63, wv = t >> 6;
  int g = lane >> 4, li = lane & 15;
  int lisw7 = li & 7;

  // smem: buf{0,1}: [K 8K | V 8K] at 0/16384
  __shared__ __align__(16) char smem[32768];

  int wq = q0 + wv * 32;
  bf16x8 qf00, qf01, qf10, qf11;
  {
    const unsigned short* qp0 = qkv + (tb + wq + li) * 1536 + h * 64 + g * 8;
    qf00 = *(const bf16x8*)qp0;
    qf01 = *(const bf16x8*)(qp0 + 32);
    const unsigned short* qp1 = qp0 + (size_t)16 * 1536;
    qf10 = *(const bf16x8*)qp1;
    qf11 = *(const bf16x8*)(qp1 + 32);
  }

  f32x4 accA[4], accB[4];
#pragma unroll
  for (int nt = 0; nt < 4; nt++) {
    accA[nt] = (f32x4){0.f, 0.f, 0.f, 0.f};
    accB[nt] = (f32x4){0.f, 0.f, 0.f, 0.f};
  }
  float lA = 0.f, lB = 0.f;

  // K read offsets: permuted rows within 32-key chunk, swizzle key (row>>2)&7
  int rowE = ((li >> 2) << 3) + (li & 3);
  int swzE = (li >> 2) << 1;
  int swzO = swzE + 1;
  int kE0 = rowE * 128 + ((g ^ swzE) << 4);
  int kE1 = rowE * 128 + (((g + 4) ^ swzE) << 4);
  int kO0 = (rowE + 4) * 128 + ((g ^ swzO) << 4);
  int kO1 = (rowE + 4) * 128 + (((g + 4) ^ swzO) << 4);
  // V region at +8192: 64 d-rows x 128B (8 slots); row=16nt+li, key ^(row&7)
  int vrowb = 8192 + li * 128;
  int vsl[2];
#pragma unroll
  for (int c = 0; c < 2; c++) vsl[c] = ((g + 4 * c) ^ lisw7) << 4;

  // staging: 8 issues of 8 rows each for K and V; 2 per wave each
  int subrow = lane >> 3;
  const unsigned short* kp[2];
  const unsigned short* vp[2];
#pragma unroll
  for (int j = 0; j < 2; j++) {
    int krow = (wv * 2 + j) * 8 + subrow;                 // 0..63
    int swzk = ((wv & 1) * 4 + 2 * j + (subrow >> 2)) & 7; // (krow>>2)&7
    kp[j] = qkv + (tb + kt0 + krow) * 1536 + 512 + h * 64
            + (((lane & 7) ^ swzk) << 3);
    int vrow = (wv * 2 + j) * 8 + subrow;                 // d 0..63
    vp[j] = Vt + ((size_t)bh * 64 + vrow) * 2048 + kt0
            + (((lane & 7) ^ (vrow & 7)) << 3);
  }

  // prologue: stage tile 0 into buf 0
#pragma unroll
  for (int j = 0; j < 2; j++) {
    gload16(kp[j], (unsigned short*)(smem + (wv * 2 + j) * 1024));
    gload16(vp[j], (unsigned short*)(smem + 8192 + (wv * 2 + j) * 1024));
    kp[j] += (size_t)64 * 1536; vp[j] += 64;
  }
  pipe_sync();

#pragma unroll 2
  for (int it = 0; it < 16; it++) {
    const int buf = it & 1;
    const char* base = smem + buf * 16384;
    if (it < 15) {
      char* nb = smem + (buf ^ 1) * 16384;
#pragma unroll
      for (int j = 0; j < 2; j++) {
        gload16(kp[j], (unsigned short*)(nb + (wv * 2 + j) * 1024));
        gload16(vp[j], (unsigned short*)(nb + 8192 + (wv * 2 + j) * 1024));
        kp[j] += (size_t)64 * 1536; vp[j] += 64;
      }
    }

    float psA = 0.f, psB = 0.f;
    const f32x4 kZ = {0.f, 0.f, 0.f, 0.f};
#pragma unroll
    for (int c = 0; c < 2; c++) {
      const char* cb_ = base + c * 4096;
      bf16x8 k0 = *(const bf16x8*)(cb_ + kE0);
      bf16x8 k1 = *(const bf16x8*)(cb_ + kE1);
      bf16x8 k2 = *(const bf16x8*)(cb_ + kO0);
      bf16x8 k3 = *(const bf16x8*)(cb_ + kO1);
      __builtin_amdgcn_s_setprio(1);
      f32x4 sEA = __builtin_amdgcn_mfma_f32_16x16x32_bf16(k0, qf00, kZ, 0, 0, 0);
      f32x4 sEB = __builtin_amdgcn_mfma_f32_16x16x32_bf16(k0, qf10, kZ, 0, 0, 0);
      f32x4 sOA = __builtin_amdgcn_mfma_f32_16x16x32_bf16(k2, qf00, kZ, 0, 0, 0);
      f32x4 sOB = __builtin_amdgcn_mfma_f32_16x16x32_bf16(k2, qf10, kZ, 0, 0, 0);
      sEA = __builtin_amdgcn_mfma_f32_16x16x32_bf16(k1, qf01, sEA, 0, 0, 0);
      sEB = __builtin_amdgcn_mfma_f32_16x16x32_bf16(k1, qf11, sEB, 0, 0, 0);
      sOA = __builtin_amdgcn_mfma_f32_16x16x32_bf16(k3, qf01, sOA, 0, 0, 0);
      sOB = __builtin_amdgcn_mfma_f32_16x16x32_bf16(k3, qf11, sOB, 0, 0, 0);
      __builtin_amdgcn_s_setprio(0);

      bf16x8 paA, paB;
#define EPACK(SE, SO, PS, PA)                                                 \
      {                                                                       \
        float e0 = SE[0], e1 = SE[1], e2 = SE[2], e3 = SE[3];                 \
        float o0 = SO[0], o1 = SO[1], o2 = SO[2], o3 = SO[3];                 \
        asm volatile("v_exp_f32 %0, %0\n\tv_exp_f32 %1, %1\n\t"               \
                     "v_exp_f32 %2, %2\n\tv_exp_f32 %3, %3\n\ts_nop 1"        \
                     : "+v"(e0), "+v"(e1), "+v"(e2), "+v"(e3));               \
        asm volatile("v_exp_f32 %0, %0\n\tv_exp_f32 %1, %1\n\t"               \
                     "v_exp_f32 %2, %2\n\tv_exp_f32 %3, %3\n\ts_nop 1"        \
                     : "+v"(o0), "+v"(o1), "+v"(o2), "+v"(o3));               \
        PS += ((e0 + e1) + (e2 + e3)) + ((o0 + o1) + (o2 + o3));              \
        unsigned int d0, d1, d2, d3;                                          \
        asm("v_cvt_pk_bf16_f32 %0, %1, %2" : "=v"(d0) : "v"(e0), "v"(e1));    \
        asm("v_cvt_pk_bf16_f32 %0, %1, %2" : "=v"(d1) : "v"(e2), "v"(e3));    \
        asm("v_cvt_pk_bf16_f32 %0, %1, %2" : "=v"(d2) : "v"(o0), "v"(o1));    \
        asm("v_cvt_pk_bf16_f32 %0, %1, %2" : "=v"(d3) : "v"(o2), "v"(o3));    \
        unsigned int tmp_[4] = {d0, d1, d2, d3};                              \
        __builtin_memcpy(&PA, tmp_, 16);                                      \
      }
      EPACK(sEA, sOA, psA, paA)
      EPACK(sEB, sOB, psB, paB)
#undef EPACK

      __builtin_amdgcn_s_setprio(1);
#pragma unroll
      for (int nt = 0; nt < 4; nt++) {
        bf16x8 vb = *(const bf16x8*)(base + vrowb + nt * 2048 + vsl[c]);
        accA[nt] = __builtin_amdgcn_mfma_f32_16x16x32_bf16(paA, vb, accA[nt], 0, 0, 0);
        accB[nt] = __builtin_amdgcn_mfma_f32_16x16x32_bf16(paB, vb, accB[nt], 0, 0, 0);
      }
      __builtin_amdgcn_s_setprio(0);
    }

    psA += swz16f(psA); psA += __shfl_xor(psA, 32); lA += psA;
    psB += swz16f(psB); psB += __shfl_xor(psB, 32); lB += psB;

    pipe_sync();
  }

  // write UNNORMALIZED partials (f32 O; f32 l PER HEAD)
  float* Ob = Op + (size_t)half * 8192 * 512;
#pragma unroll
  for (int i = 0; i < 4; i++) {
    size_t ra = (tb + wq + 4 * g + i) * 512 + h * 64;
    size_t rb = (tb + wq + 16 + 4 * g + i) * 512 + h * 64;
#pragma unroll
    for (int nt = 0; nt < 4; nt++) {
      Ob[ra + 16 * nt + li] = accA[nt][i];
      Ob[rb + 16 * nt + li] = accB[nt][i];
    }
  }
  if (g == 0) {
    size_t lbase = ((size_t)(half * 8 + h)) * 8192;
    Lp[lbase + tb + wq + li]      = lA;
    Lp[lbase + tb + wq + 16 + li] = lB;
  }
}

// ---- combine split-K partials: ctx[row][h*64+..] = (O0+O1)/(l0[h]+l1[h]) ----
__global__ __launch_bounds__(256) void attn_combine(
    const float* __restrict__ Op, const float* __restrict__ Lp,
    unsigned short* __restrict__ ctx)
{
  int t = threadIdx.x, lane = t & 63, wv = t >> 6;
  size_t row = (size_t)blockIdx.x * 4 + wv;
  int h = lane >> 3;                         // 8 cols/lane, 64 cols/head
  float inv = 1.f / (Lp[(size_t)h * 8192 + row] +
                     Lp[(size_t)(8 + h) * 8192 + row]);
  const float* p1 = Op + row * 512 + lane * 8;
  const float* p2 = p1 + (size_t)8192 * 512;
  float4 a0 = *(const float4*)p1;
  float4 a1 = *(const float4*)(p1 + 4);
  float4 c0 = *(const float4*)p2;
  float4 c1 = *(const float4*)(p2 + 4);
  float vals[8] = {(a0.x + c0.x) * inv, (a0.y + c0.y) * inv,
                   (a0.z + c0.z) * inv, (a0.w + c0.w) * inv,
                   (a1.x + c1.x) * inv, (a1.y + c1.y) * inv,
                   (a1.z + c1.z) * inv, (a1.w + c1.w) * inv};
  bf16x8 o;
#pragma unroll
  for (int j = 0; j < 8; j++) o[j] = (short)f2bf(vals[j]);
  *(bf16x8*)(ctx + row * 512 + lane * 8) = o;
}

// ---------------- LayerNorm over E=512 (bf16 in, bf16 out); one wave/row -----
__global__ __launch_bounds__(256) void ln_kernel(
    const unsigned short* __restrict__ X, const float* __restrict__ g,
    const float* __restrict__ b, unsigned short* __restrict__ Yb)
{
  int t = threadIdx.x, lane = t & 63, wv = t >> 6;
  size_t row = (size_t)blockIdx.x * 4 + wv;
  bf16x8 xv = *(const bf16x8*)(X + row * 512 + lane * 8);
  float xf[8];
#pragma unroll
  for (int j = 0; j < 8; j++) xf[j] = bf2f((unsigned short)xv[j]);
  float sum = 0.f, sq = 0.f;
#pragma unroll
  for (int j = 0; j < 8; j++) { sum += xf[j]; sq += xf[j] * xf[j]; }
#pragma unroll
  for (int off = 32; off > 0; off >>= 1) {
    sum += __shfl_xor(sum, off);
    sq  += __shfl_xor(sq, off);
  }
  float mu  = sum * (1.0f / 512.0f);
  float inv = rsqrtf(sq * (1.0f / 512.0f) - mu * mu + 1e-5f);
  float4 g0 = *(const float4*)(g + lane * 8);
  float4 g1 = *(const float4*)(g + lane * 8 + 4);
  float4 b0 = *(const float4*)(b + lane * 8);
  float4 b1 = *(const float4*)(b + lane * 8 + 4);
  float gw[8] = {g0.x, g0.y, g0.z, g0.w, g1.x, g1.y, g1.z, g1.w};
  float bw[8] = {b0.x, b0.y, b0.z, b0.w, b1.x, b1.y, b1.z, b1.w};
  bf16x8 yb;
#pragma unroll
  for (int j = 0; j < 8; j++)
    yb[j] = (short)f2bf((xf[j] - mu) * inv * gw[j] + bw[j]);
  *(bf16x8*)(Yb + row * 512 + lane * 8) = yb;
}

extern "C" void kernel_launch(void* const* d_in, const int* in_sizes, int n_in,
                              void* d_out, int out_size, void* d_ws, size_t ws_size,
                              hipStream_t stream) {
  (void)in_sizes; (void)n_in; (void)out_size; (void)ws_size;
  const float* x      = (const float*)d_in[0];
  const float* conv_w = (const float*)d_in[1];
  const float* conv_b = (const float*)d_in[2];
  const float* qkv_w  = (const float*)d_in[3];
  const float* qkv_b  = (const float*)d_in[4];
  const float* out_w  = (const float*)d_in[5];
  const float* out_b  = (const float*)d_in[6];
  const float* fc1_w  = (const float*)d_in[7];
  const float* fc1_b  = (const float*)d_in[8];
  const float* fc2_w  = (const float*)d_in[9];
  const float* fc2_b  = (const float*)d_in[10];
  const float* ln1_w  = (const float*)d_in[11];
  const float* ln1_b  = (const float*)d_in[12];
  const float* ln2_w  = (const float*)d_in[13];
  const float* ln2_b  = (const float*)d_in[14];
  const float* outp_w = (const float*)d_in[15];
  const float* outp_b = (const float*)d_in[16];
  float* out = (float*)d_out;

  char* p = (char*)d_ws;
  unsigned short* A    = (unsigned short*)p;            p += (size_t)8192 * 512 * 2;
  unsigned short* QKV  = (unsigned short*)p;            p += (size_t)8192 * 1536 * 2;
  unsigned short* VT   = (unsigned short*)p;            p += (size_t)32 * 64 * 2048 * 2;
  unsigned short* CTX  = (unsigned short*)p;            p += (size_t)8192 * 512 * 2;
  unsigned short* Wq   = (unsigned short*)p;            p += (size_t)4 * 1536 * 512 * 2;
  unsigned short* Wo   = (unsigned short*)p;            p += (size_t)4 * 512 * 512 * 2;
  unsigned short* W1   = (unsigned short*)p;            p += (size_t)4 * 512 * 512 * 2;
  unsigned short* W2   = (unsigned short*)p;            p += (size_t)4 * 512 * 512 * 2;
  unsigned short* Wp   = (unsigned short*)p;            p += (size_t)32 * 512 * 2;
  float*          OP   = (float*)p;                     p += (size_t)2 * 8192 * 512 * 4;
  float*          LP   = (float*)p;                     p += (size_t)2 * 8 * 8192 * 4;
  unsigned short* D = QKV;   // aliased: D[8192,512] bf16 in QKV region (disjoint lifetime)

  cvt_all<<<6160, 256, 0, stream>>>(qkv_w, out_w, fc1_w, fc2_w, outp_w, Wq);

  conv_pe_kernel<<<1024, 256, 0, stream>>>(x, conv_w, conv_b, A);

  for (int l = 0; l < 4; l++) {
    gemm_bf<0, 1, 4, 1><<<64 * 12, 256, 0, stream>>>(
        A, Wq + (size_t)l * 1536 * 512, qkv_b + l * 1536, nullptr,
        QKV, nullptr, VT, 1536);
    attn_mfma<<<1024, 256, 0, stream>>>(QKV, VT, OP, LP);
    attn_combine<<<2048, 256, 0, stream>>>(OP, LP, CTX);
    gemm_bf<1, 0, 2, 0><<<64 * 8, 256, 0, stream>>>(
        CTX, Wo + (size_t)l * 512 * 512, out_b + l * 512, A,
        D, nullptr, nullptr, 512);
    ln_kernel<<<2048, 256, 0, stream>>>(D, ln1_w + l * 512, ln1_b + l * 512, A);
    gemm_bf<2, 0, 2, 0><<<64 * 8, 256, 0, stream>>>(
        A, W1 + (size_t)l * 512 * 512, fc1_b + l * 512, nullptr,
        CTX, nullptr, nullptr, 512);
    gemm_bf<1, 0, 2, 0><<<64 * 8, 256, 0, stream>>>(
        CTX, W2 + (size_t)l * 512 * 512, fc2_b + l * 512, A,
        D, nullptr, nullptr, 512);
    ln_kernel<<<2048, 256, 0, stream>>>(D, ln2_w + l * 512, ln2_b + l * 512, A);
  }
  gemm_bf<3, 0, 1, 0><<<64, 256, 0, stream>>>(
      A, Wp, outp_b, nullptr, nullptr, out, nullptr, 32);
}

// Round 21
// 462.969 us; speedup vs baseline: 1.0955x; 1.0955x over previous
//
#include <hip/hip_runtime.h>
#include <hip/hip_bf16.h>
#include <cstddef>

typedef short bf16x8 __attribute__((ext_vector_type(8)));
typedef float f32x4 __attribute__((ext_vector_type(4)));

__device__ __forceinline__ unsigned short f2bf(float x) {
  __hip_bfloat16 h = __float2bfloat16(x);
  unsigned short u; __builtin_memcpy(&u, &h, 2); return u;
}
__device__ __forceinline__ float bf2f(unsigned short u) {
  unsigned int v = ((unsigned int)u) << 16; float f; __builtin_memcpy(&f, &v, 4); return f;
}
__device__ __forceinline__ float swz16f(float x) {   // lane ^= 16 (within 32-group)
  int i; __builtin_memcpy(&i, &x, 4);
  i = __builtin_amdgcn_ds_swizzle(i, 0x401F);
  float r; __builtin_memcpy(&r, &i, 4); return r;
}
__device__ __forceinline__ void gload16(const unsigned short* g, unsigned short* l) {
  __builtin_amdgcn_global_load_lds(
      (const __attribute__((address_space(1))) void*)g,
      (__attribute__((address_space(3))) void*)l, 16, 0, 0);
}
__device__ __forceinline__ void pipe_sync() {
  asm volatile("s_waitcnt vmcnt(0)" ::: "memory");
  __builtin_amdgcn_s_barrier();
  __builtin_amdgcn_sched_barrier(0);
}
__device__ __forceinline__ void bar_only() {
  asm volatile("" ::: "memory");
  __builtin_amdgcn_s_barrier();
  __builtin_amdgcn_sched_barrier(0);
}

// ---------------- all weights fp32 -> bf16 (contiguous dst) ----------------
__global__ __launch_bounds__(256) void cvt_all(
    const float* __restrict__ qkv_w, const float* __restrict__ out_w,
    const float* __restrict__ fc1_w, const float* __restrict__ fc2_w,
    const float* __restrict__ outp_w, unsigned short* __restrict__ dst)
{
  int i = blockIdx.x * 256 + threadIdx.x;
  if (i >= 1576960) return;
  const float* src; int off;
  if (i < 786432)       { src = qkv_w;  off = i; }
  else if (i < 1048576) { src = out_w;  off = i - 786432; }
  else if (i < 1310720) { src = fc1_w;  off = i - 1048576; }
  else if (i < 1572864) { src = fc2_w;  off = i - 1310720; }
  else                  { src = outp_w; off = i - 1572864; }
  float4 v = *(const float4*)(src + (size_t)off * 4);
  ushort4 o;
  o.x = f2bf(v.x); o.y = f2bf(v.y); o.z = f2bf(v.z); o.w = f2bf(v.w);
  *(ushort4*)(dst + (size_t)i * 4) = o;
}

// ---------------- conv1d (circular, k=3) + positional embedding -> bf16 ------
__global__ __launch_bounds__(256) void conv_pe_kernel(
    const float* __restrict__ x, const float* __restrict__ cw,
    const float* __restrict__ cb, unsigned short* __restrict__ outb)
{
  const int L = 2048, CIN = 32;
  int b  = blockIdx.x >> 8;
  int l0 = (blockIdx.x & 255) << 3;
  int t  = threadIdx.x;
  __shared__ float xs[10][32];
  for (int idx = t; idx < 320; idx += 256) {
    int rr = idx >> 5, ci = idx & 31;
    int gl = (l0 - 1 + rr + L) & (L - 1);
    xs[rr][ci] = x[((size_t)b * L + gl) * CIN + ci];
  }
  __syncthreads();
  int e0 = t << 1;
  float acc0[8], acc1[8];
  float bb0 = cb[e0], bb1 = cb[e0 + 1];
#pragma unroll
  for (int li = 0; li < 8; li++) { acc0[li] = bb0; acc1[li] = bb1; }
  const float* w0p = cw + (size_t)e0 * 96;
  const float* w1p = w0p + 96;
  for (int ci = 0; ci < 32; ci++) {
#pragma unroll
    for (int kk = 0; kk < 3; kk++) {
      float w0 = w0p[ci * 3 + kk];
      float w1 = w1p[ci * 3 + kk];
#pragma unroll
      for (int li = 0; li < 8; li++) {
        float xv = xs[li + kk][ci];
        acc0[li] += xv * w0;
        acc1[li] += xv * w1;
      }
    }
  }
  float dv = __expf((float)e0 * (-9.210340371976184f / 512.0f));
#pragma unroll
  for (int li = 0; li < 8; li++) {
    int l = l0 + li;
    float arg = (float)l * dv;
    float sv = __sinf(arg), cv = __cosf(arg);   // native v_sin/v_cos path
    size_t off = ((size_t)b * L + l) * 512 + e0;
    ushort2 ob; ob.x = f2bf(acc0[li] + sv); ob.y = f2bf(acc1[li] + cv);
    *(ushort2*)&outb[off] = ob;
  }
}

// ---------------- bf16 MFMA GEMM, 2-phase pipelined, counted vmcnt (T4) ------
// Y[M,N] = X[M,512] @ W[N,512]^T + bias.  Tile 128 x (NFR*32).
// EPI 0: Yb bf16 (QSCALE: cols<512 prescaled).  EPI 1: Yb bf16 = +R(bf16).
// EPI 2: SiLU->Yb.  EPI 3: Yf f32 (no residual).
// VOUT: n-blocks with n0>=1024 write TRANSPOSED into VT[32][64][2048] (V path).
template<int EPI, int QSCALE, int NFR, int VOUT>
__global__ __launch_bounds__(256) void gemm_bf(
    const unsigned short* __restrict__ X,
    const unsigned short* __restrict__ W,
    const float* __restrict__ bias,
    const unsigned short* __restrict__ R,
    unsigned short* __restrict__ Yb,
    float* __restrict__ Yf,
    unsigned short* __restrict__ VT,
    int N)
{
  const int K = 512;
  constexpr int BN = NFR * 32;
  constexpr int WB = NFR * 4096;          // W-region bytes per buffer
  constexpr int BUF = 16384 + WB;
  __shared__ __align__(16) char smem[2 * BUF];
  int t = threadIdx.x;
  int lane = t & 63, wv = t >> 6;
  int g = lane >> 4, li = lane & 15;
  int m0 = (blockIdx.x & 63) << 7;
  int n0 = (blockIdx.x >> 6) * BN;
  int wm = (wv >> 1) << 6;
  int wn = (wv & 1) * (BN / 2);

  int subrow = lane >> 3;
  int coloff = ((lane & 7) ^ subrow) << 3;   // inverse swizzle on global source

  f32x4 acc[4][NFR];
#pragma unroll
  for (int a = 0; a < 4; a++)
#pragma unroll
    for (int b2 = 0; b2 < NFR; b2++) acc[a][b2] = (f32x4){0.f, 0.f, 0.f, 0.f};

  // prologue: stage k-step 0 into buf 0 (no drain: first-iter vmcnt covers it)
#pragma unroll
  for (int j = 0; j < 4; j++) {
    int row = (wv * 4 + j) * 8 + subrow;
    gload16(X + (size_t)(m0 + row) * K + coloff,
            (unsigned short*)(smem + (wv * 4 + j) * 1024));
  }
#pragma unroll
  for (int j = 0; j < NFR; j++) {
    int row = (wv * NFR + j) * 8 + subrow;
    gload16(W + (size_t)(n0 + row) * K + coloff,
            (unsigned short*)(smem + 16384 + (wv * NFR + j) * 1024));
  }

#pragma unroll
  for (int ks = 0; ks < 8; ks++) {
    const int buf = ks & 1;
    char* cur = smem + buf * BUF;
    if (ks < 7) {                     // issue next-tile loads first
      char* nxt = smem + (buf ^ 1) * BUF;
      int k0 = (ks + 1) * 64;
#pragma unroll
      for (int j = 0; j < 4; j++) {
        int row = (wv * 4 + j) * 8 + subrow;
        gload16(X + (size_t)(m0 + row) * K + k0 + coloff,
                (unsigned short*)(nxt + (wv * 4 + j) * 1024));
      }
#pragma unroll
      for (int j = 0; j < NFR; j++) {
        int row = (wv * NFR + j) * 8 + subrow;
        gload16(W + (size_t)(n0 + row) * K + k0 + coloff,
                (unsigned short*)(nxt + 16384 + (wv * NFR + j) * 1024));
      }
      // counted wait: only tile-ks loads (oldest) must land; next tile's stay in flight
      if constexpr (NFR == 4) asm volatile("s_waitcnt vmcnt(8)" ::: "memory");
      else if constexpr (NFR == 2) asm volatile("s_waitcnt vmcnt(6)" ::: "memory");
      else asm volatile("s_waitcnt vmcnt(5)" ::: "memory");
    } else {
      asm volatile("s_waitcnt vmcnt(0)" ::: "memory");
    }
    __builtin_amdgcn_s_barrier();          // all waves' tile-ks data visible
    __builtin_amdgcn_sched_barrier(0);

#pragma unroll
    for (int s = 0; s < 2; s++) {
      bf16x8 af[4], bfr[NFR];
#pragma unroll
      for (int mt = 0; mt < 4; mt++) {
        int row = wm + 16 * mt + li;
        af[mt] = *(const bf16x8*)(cur + (row * 8 + ((g + 4 * s) ^ (row & 7))) * 16);
      }
#pragma unroll
      for (int nt = 0; nt < NFR; nt++) {
        int row = wn + 16 * nt + li;
        bfr[nt] = *(const bf16x8*)(cur + 16384 +
                                   (row * 8 + ((g + 4 * s) ^ (row & 7))) * 16);
      }
#pragma unroll
      for (int mt = 0; mt < 4; mt++)
#pragma unroll
        for (int nt = 0; nt < NFR; nt++)
          acc[mt][nt] = __builtin_amdgcn_mfma_f32_16x16x32_bf16(
              af[mt], bfr[nt], acc[mt][nt], 0, 0, 0);
    }
    if (ks < 7) bar_only();                // guard buffer overwrite by iter ks+1's issues
  }

  float bv[NFR];
#pragma unroll
  for (int nt = 0; nt < NFR; nt++) bv[nt] = bias[n0 + wn + 16 * nt + li];

  if (VOUT && n0 >= 1024) {
    // transposed V output: LDS bounce (rows = tile cols, stride 136 shorts)
    unsigned short* Ts = (unsigned short*)smem;
    __builtin_amdgcn_s_barrier();          // all compute reads of smem done
#pragma unroll
    for (int nt = 0; nt < NFR; nt++) {
      int col = wn + 16 * nt + li;
      float bvn = bv[nt];
#pragma unroll
      for (int mt = 0; mt < 4; mt++) {
        float v0 = acc[mt][nt][0] + bvn, v1 = acc[mt][nt][1] + bvn;
        float v2 = acc[mt][nt][2] + bvn, v3 = acc[mt][nt][3] + bvn;
        uint2 pk;
        asm("v_cvt_pk_bf16_f32 %0, %1, %2" : "=v"(pk.x) : "v"(v0), "v"(v1));
        asm("v_cvt_pk_bf16_f32 %0, %1, %2" : "=v"(pk.y) : "v"(v2), "v"(v3));
        *(uint2*)(Ts + col * 136 + wm + 16 * mt + 4 * g) = pk;
      }
    }
    __syncthreads();
    int vcol = t >> 1, half = t & 1;
    int gc = n0 - 1024 + vcol;
    int bh = (m0 >> 11) * 8 + (gc >> 6);
    int d  = gc & 63;
    unsigned short* dst = VT + ((size_t)bh * 64 + d) * 2048 + (m0 & 2047) + half * 64;
    const unsigned short* srcp = Ts + vcol * 136 + half * 64;
#pragma unroll
    for (int j2 = 0; j2 < 8; j2++)
      *(bf16x8*)(dst + j2 * 8) = *(const bf16x8*)(srcp + j2 * 8);
    return;
  }

#pragma unroll
  for (int mt = 0; mt < 4; mt++) {
#pragma unroll
    for (int i = 0; i < 4; i++) {
      size_t roff = (size_t)(m0 + wm + 16 * mt + 4 * g + i) * N;
#pragma unroll
      for (int nt = 0; nt < NFR; nt++) {
        int col = n0 + wn + 16 * nt + li;
        float v = acc[mt][nt][i] + bv[nt];
        if (EPI == 1) {
          v += bf2f(R[roff + col]);
          Yb[roff + col] = f2bf(v);
        } else if (EPI == 2) {
          v = v / (1.f + __expf(-v));
          Yb[roff + col] = f2bf(v);
        } else if (EPI == 3) {
          Yf[roff + col] = v;
        } else {
          if (QSCALE && col < 512) v *= 0.18033688011112042f;  // 0.125*log2(e)
          Yb[roff + col] = f2bf(v);
        }
      }
    }
  }
}

// ---------------- MFMA flash attention: in-register P, per-chunk schedule ----
// QBLK=128, KVBLK=128; grid 512: bh = bid&31 (XCD-local), qi = bid>>5; 4 waves.
// Q prescaled by 0.125*log2(e); NO-MAX softmax (p = 2^s directly).
// K-row permutation: frag loads K rows 8*(r>>2)+(r&3)+4*odd+32*c so lane holds
// scores for keys 32c+8g+j, q=li == PV A-frag layout; P never touches LDS.
// Per-chunk c: QK(8 mfma) -> exp/pack -> PV(8 mfma) bounds live registers.
__global__ __launch_bounds__(256) void attn_mfma(
    const unsigned short* __restrict__ qkv,  // [8192,1536] bf16
    const unsigned short* __restrict__ Vt,   // [32,64,2048] bf16
    unsigned short* __restrict__ ctx)        // [8192,512] bf16
{
  const int L = 2048;
  int bh = blockIdx.x & 31, qi = blockIdx.x >> 5;   // same-bh blocks -> same XCD
  int b = bh >> 3, h = bh & 7;
  int q0 = qi << 7;
  size_t tb = (size_t)b * L;
  int t = threadIdx.x, lane = t & 63, wv = t >> 6;
  int g = lane >> 4, li = lane & 15;
  int lisw7 = li & 7;

  // smem: buf{0,1}: [K 16K | V 16K] at 0/32768  (no P region)
  __shared__ __align__(16) char smem[65536];

  int wq = q0 + wv * 32;
  bf16x8 qf00, qf01, qf10, qf11;
  {
    const unsigned short* qp0 = qkv + (tb + wq + li) * 1536 + h * 64 + g * 8;
    qf00 = *(const bf16x8*)qp0;
    qf01 = *(const bf16x8*)(qp0 + 32);
    const unsigned short* qp1 = qp0 + (size_t)16 * 1536;
    qf10 = *(const bf16x8*)qp1;
    qf11 = *(const bf16x8*)(qp1 + 32);
  }

  f32x4 accA[4], accB[4];
#pragma unroll
  for (int nt = 0; nt < 4; nt++) {
    accA[nt] = (f32x4){0.f, 0.f, 0.f, 0.f};
    accB[nt] = (f32x4){0.f, 0.f, 0.f, 0.f};
  }
  float lA = 0.f, lB = 0.f;

  // K read offsets: permuted rows, swizzle key (row>>2)&7
  int rowE = ((li >> 2) << 3) + (li & 3);
  int swzE = (li >> 2) << 1;           // (rowE>>2)&7
  int swzO = swzE + 1;                 // ((rowE+4)>>2)&7
  int kE0 = rowE * 128 + ((g ^ swzE) << 4);
  int kE1 = rowE * 128 + (((g + 4) ^ swzE) << 4);
  int kO0 = (rowE + 4) * 128 + ((g ^ swzO) << 4);
  int kO1 = (rowE + 4) * 128 + (((g + 4) ^ swzO) << 4);
  // V fragment offsets (V region rows = 256B, 16 slots): row = 16nt+li, key ^(row&7)
  int vrowb = 16384 + li * 256;
  int vsl[4];
#pragma unroll
  for (int c = 0; c < 4; c++) vsl[c] = ((g + 4 * c) ^ lisw7) << 4;

  // staging pointers: K swizzle key (2j + subrow>>2)&7 ; V swizzle key row&7
  int subrow = lane >> 3;
  const unsigned short* kp[4];
  const unsigned short* vp[4];
#pragma unroll
  for (int j = 0; j < 4; j++) {
    int krow = (wv * 4 + j) * 8 + subrow;
    int swzk = (2 * j + (subrow >> 2)) & 7;
    kp[j] = qkv + (tb + krow) * 1536 + 512 + h * 64 + (((lane & 7) ^ swzk) << 3);
    int vrow = (wv * 4 + j) * 4 + g;
    vp[j] = Vt + ((size_t)bh * 64 + vrow) * 2048 + ((li ^ (vrow & 7)) << 3);
  }

  // prologue: stage tile 0 into buf 0
#pragma unroll
  for (int j = 0; j < 4; j++) {
    gload16(kp[j], (unsigned short*)(smem + (wv * 4 + j) * 1024));
    gload16(vp[j], (unsigned short*)(smem + 16384 + (wv * 4 + j) * 1024));
    kp[j] += (size_t)128 * 1536; vp[j] += 128;
  }
  pipe_sync();

#pragma unroll 2
  for (int it = 0; it < 16; it++) {
    const int buf = it & 1;
    const char* base = smem + buf * 32768;
    if (it < 15) {                    // issue next tile first (latency hides)
      char* nb = smem + (buf ^ 1) * 32768;
#pragma unroll
      for (int j = 0; j < 4; j++) {
        gload16(kp[j], (unsigned short*)(nb + (wv * 4 + j) * 1024));
        gload16(vp[j], (unsigned short*)(nb + 16384 + (wv * 4 + j) * 1024));
        kp[j] += (size_t)128 * 1536; vp[j] += 128;
      }
    }

    float psA = 0.f, psB = 0.f;
    const f32x4 kZ = {0.f, 0.f, 0.f, 0.f};
#pragma unroll
    for (int c = 0; c < 4; c++) {
      const char* cb_ = base + c * 4096;
      // QK: 8 MFMA -> this chunk's scores (keys 32c+8g+0..7, q=li)
      bf16x8 k0 = *(const bf16x8*)(cb_ + kE0);
      bf16x8 k1 = *(const bf16x8*)(cb_ + kE1);
      bf16x8 k2 = *(const bf16x8*)(cb_ + kO0);
      bf16x8 k3 = *(const bf16x8*)(cb_ + kO1);
      __builtin_amdgcn_s_setprio(1);
      f32x4 sEA = __builtin_amdgcn_mfma_f32_16x16x32_bf16(k0, qf00, kZ, 0, 0, 0);
      f32x4 sEB = __builtin_amdgcn_mfma_f32_16x16x32_bf16(k0, qf10, kZ, 0, 0, 0);
      f32x4 sOA = __builtin_amdgcn_mfma_f32_16x16x32_bf16(k2, qf00, kZ, 0, 0, 0);
      f32x4 sOB = __builtin_amdgcn_mfma_f32_16x16x32_bf16(k2, qf10, kZ, 0, 0, 0);
      sEA = __builtin_amdgcn_mfma_f32_16x16x32_bf16(k1, qf01, sEA, 0, 0, 0);
      sEB = __builtin_amdgcn_mfma_f32_16x16x32_bf16(k1, qf11, sEB, 0, 0, 0);
      sOA = __builtin_amdgcn_mfma_f32_16x16x32_bf16(k3, qf01, sOA, 0, 0, 0);
      sOB = __builtin_amdgcn_mfma_f32_16x16x32_bf16(k3, qf11, sOB, 0, 0, 0);
      __builtin_amdgcn_s_setprio(0);

      // exp + pack straight into PV A-fragments (registers only)
      bf16x8 paA, paB;
#define EPACK(SE, SO, PS, PA)                                                 \
      {                                                                       \
        float e0 = SE[0], e1 = SE[1], e2 = SE[2], e3 = SE[3];                 \
        float o0 = SO[0], o1 = SO[1], o2 = SO[2], o3 = SO[3];                 \
        asm volatile("v_exp_f32 %0, %0\n\tv_exp_f32 %1, %1\n\t"               \
                     "v_exp_f32 %2, %2\n\tv_exp_f32 %3, %3\n\ts_nop 1"        \
                     : "+v"(e0), "+v"(e1), "+v"(e2), "+v"(e3));               \
        asm volatile("v_exp_f32 %0, %0\n\tv_exp_f32 %1, %1\n\t"               \
                     "v_exp_f32 %2, %2\n\tv_exp_f32 %3, %3\n\ts_nop 1"        \
                     : "+v"(o0), "+v"(o1), "+v"(o2), "+v"(o3));               \
        PS += ((e0 + e1) + (e2 + e3)) + ((o0 + o1) + (o2 + o3));              \
        unsigned int d0, d1, d2, d3;                                          \
        asm("v_cvt_pk_bf16_f32 %0, %1, %2" : "=v"(d0) : "v"(e0), "v"(e1));    \
        asm("v_cvt_pk_bf16_f32 %0, %1, %2" : "=v"(d1) : "v"(e2), "v"(e3));    \
        asm("v_cvt_pk_bf16_f32 %0, %1, %2" : "=v"(d2) : "v"(o0), "v"(o1));    \
        asm("v_cvt_pk_bf16_f32 %0, %1, %2" : "=v"(d3) : "v"(o2), "v"(o3));    \
        unsigned int tmp_[4] = {d0, d1, d2, d3};                              \
        __builtin_memcpy(&PA, tmp_, 16);                                      \
      }
      EPACK(sEA, sOA, psA, paA)
      EPACK(sEB, sOB, psB, paB)
#undef EPACK

      // PV: 8 MFMA for this chunk; vb shared across both q-frags
      __builtin_amdgcn_s_setprio(1);
#pragma unroll
      for (int nt = 0; nt < 4; nt++) {
        bf16x8 vb = *(const bf16x8*)(base + vrowb + nt * 4096 + vsl[c]);
        accA[nt] = __builtin_amdgcn_mfma_f32_16x16x32_bf16(paA, vb, accA[nt], 0, 0, 0);
        accB[nt] = __builtin_amdgcn_mfma_f32_16x16x32_bf16(paB, vb, accB[nt], 0, 0, 0);
      }
      __builtin_amdgcn_s_setprio(0);
    }

    psA += swz16f(psA); psA += __shfl_xor(psA, 32); lA += psA;
    psB += swz16f(psB); psB += __shfl_xor(psB, 32); lB += psB;

    pipe_sync();
  }

  float liA[4], liB[4];
#pragma unroll
  for (int i = 0; i < 4; i++) {
    liA[i] = 1.f / __shfl(lA, 4 * g + i);
    liB[i] = 1.f / __shfl(lB, 4 * g + i);
  }
#pragma unroll
  for (int i = 0; i < 4; i++) {
    size_t ra = (tb + wq + 4 * g + i) * 512 + h * 64;
    size_t rb = (tb + wq + 16 + 4 * g + i) * 512 + h * 64;
#pragma unroll
    for (int nt = 0; nt < 4; nt++) {
      ctx[ra + 16 * nt + li] = f2bf(accA[nt][i] * liA[i]);
      ctx[rb + 16 * nt + li] = f2bf(accB[nt][i] * liB[i]);
    }
  }
}

// ---------------- LayerNorm over E=512 (bf16 in, bf16 out); one wave/row -----
__global__ __launch_bounds__(256) void ln_kernel(
    const unsigned short* __restrict__ X, const float* __restrict__ g,
    const float* __restrict__ b, unsigned short* __restrict__ Yb)
{
  int t = threadIdx.x, lane = t & 63, wv = t >> 6;
  size_t row = (size_t)blockIdx.x * 4 + wv;
  bf16x8 xv = *(const bf16x8*)(X + row * 512 + lane * 8);
  float xf[8];
#pragma unroll
  for (int j = 0; j < 8; j++) xf[j] = bf2f((unsigned short)xv[j]);
  float sum = 0.f, sq = 0.f;
#pragma unroll
  for (int j = 0; j < 8; j++) { sum += xf[j]; sq += xf[j] * xf[j]; }
#pragma unroll
  for (int off = 32; off > 0; off >>= 1) {
    sum += __shfl_xor(sum, off);
    sq  += __shfl_xor(sq, off);
  }
  float mu  = sum * (1.0f / 512.0f);
  float inv = rsqrtf(sq * (1.0f / 512.0f) - mu * mu + 1e-5f);
  float4 g0 = *(const float4*)(g + lane * 8);
  float4 g1 = *(const float4*)(g + lane * 8 + 4);
  float4 b0 = *(const float4*)(b + lane * 8);
  float4 b1 = *(const float4*)(b + lane * 8 + 4);
  float gw[8] = {g0.x, g0.y, g0.z, g0.w, g1.x, g1.y, g1.z, g1.w};
  float bw[8] = {b0.x, b0.y, b0.z, b0.w, b1.x, b1.y, b1.z, b1.w};
  bf16x8 yb;
#pragma unroll
  for (int j = 0; j < 8; j++)
    yb[j] = (short)f2bf((xf[j] - mu) * inv * gw[j] + bw[j]);
  *(bf16x8*)(Yb + row * 512 + lane * 8) = yb;
}

extern "C" void kernel_launch(void* const* d_in, const int* in_sizes, int n_in,
                              void* d_out, int out_size, void* d_ws, size_t ws_size,
                              hipStream_t stream) {
  (void)in_sizes; (void)n_in; (void)out_size; (void)ws_size;
  const float* x      = (const float*)d_in[0];
  const float* conv_w = (const float*)d_in[1];
  const float* conv_b = (const float*)d_in[2];
  const float* qkv_w  = (const float*)d_in[3];
  const float* qkv_b  = (const float*)d_in[4];
  const float* out_w  = (const float*)d_in[5];
  const float* out_b  = (const float*)d_in[6];
  const float* fc1_w  = (const float*)d_in[7];
  const float* fc1_b  = (const float*)d_in[8];
  const float* fc2_w  = (const float*)d_in[9];
  const float* fc2_b  = (const float*)d_in[10];
  const float* ln1_w  = (const float*)d_in[11];
  const float* ln1_b  = (const float*)d_in[12];
  const float* ln2_w  = (const float*)d_in[13];
  const float* ln2_b  = (const float*)d_in[14];
  const float* outp_w = (const float*)d_in[15];
  const float* outp_b = (const float*)d_in[16];
  float* out = (float*)d_out;

  char* p = (char*)d_ws;
  unsigned short* A    = (unsigned short*)p;            p += (size_t)8192 * 512 * 2;
  unsigned short* QKV  = (unsigned short*)p;            p += (size_t)8192 * 1536 * 2;
  unsigned short* VT   = (unsigned short*)p;            p += (size_t)32 * 64 * 2048 * 2;
  unsigned short* CTX  = (unsigned short*)p;            p += (size_t)8192 * 512 * 2;
  unsigned short* Wq   = (unsigned short*)p;            p += (size_t)4 * 1536 * 512 * 2;
  unsigned short* Wo   = (unsigned short*)p;            p += (size_t)4 * 512 * 512 * 2;
  unsigned short* W1   = (unsigned short*)p;            p += (size_t)4 * 512 * 512 * 2;
  unsigned short* W2   = (unsigned short*)p;            p += (size_t)4 * 512 * 512 * 2;
  unsigned short* Wp   = (unsigned short*)p;            p += (size_t)32 * 512 * 2;
  unsigned short* D = QKV;   // aliased: D[8192,512] bf16 in QKV region (disjoint lifetime)

  cvt_all<<<6160, 256, 0, stream>>>(qkv_w, out_w, fc1_w, fc2_w, outp_w, Wq);

  conv_pe_kernel<<<1024, 256, 0, stream>>>(x, conv_w, conv_b, A);

  for (int l = 0; l < 4; l++) {
    gemm_bf<0, 1, 4, 1><<<64 * 12, 256, 0, stream>>>(
        A, Wq + (size_t)l * 1536 * 512, qkv_b + l * 1536, nullptr,
        QKV, nullptr, VT, 1536);
    attn_mfma<<<512, 256, 0, stream>>>(QKV, VT, CTX);
    gemm_bf<1, 0, 2, 0><<<64 * 8, 256, 0, stream>>>(
        CTX, Wo + (size_t)l * 512 * 512, out_b + l * 512, A,
        D, nullptr, nullptr, 512);
    ln_kernel<<<2048, 256, 0, stream>>>(D, ln1_w + l * 512, ln1_b + l * 512, A);
    gemm_bf<2, 0, 2, 0><<<64 * 8, 256, 0, stream>>>(
        A, W1 + (size_t)l * 512 * 512, fc1_b + l * 512, nullptr,
        CTX, nullptr, nullptr, 512);
    gemm_bf<1, 0, 2, 0><<<64 * 8, 256, 0, stream>>>(
        CTX, W2 + (size_t)l * 512 * 512, fc2_b + l * 512, A,
        D, nullptr, nullptr, 512);
    ln_kernel<<<2048, 256, 0, stream>>>(D, ln2_w + l * 512, ln2_b + l * 512, A);
  }
  gemm_bf<3, 0, 1, 0><<<64, 256, 0, stream>>>(
      A, Wp, outp_b, nullptr, nullptr, out, nullptr, 32);
}

// Round 22
// 454.396 us; speedup vs baseline: 1.1162x; 1.0189x over previous
//
#include <hip/hip_runtime.h>
#include <hip/hip_bf16.h>
#include <cstddef>

typedef short bf16x8 __attribute__((ext_vector_type(8)));
typedef float f32x4 __attribute__((ext_vector_type(4)));

__device__ __forceinline__ unsigned short f2bf(float x) {
  __hip_bfloat16 h = __float2bfloat16(x);
  unsigned short u; __builtin_memcpy(&u, &h, 2); return u;
}
__device__ __forceinline__ float bf2f(unsigned short u) {
  unsigned int v = ((unsigned int)u) << 16; float f; __builtin_memcpy(&f, &v, 4); return f;
}
__device__ __forceinline__ void gload16(const unsigned short* g, unsigned short* l) {
  __builtin_amdgcn_global_load_lds(
      (const __attribute__((address_space(1))) void*)g,
      (__attribute__((address_space(3))) void*)l, 16, 0, 0);
}
__device__ __forceinline__ void pipe_sync() {
  asm volatile("s_waitcnt vmcnt(0)" ::: "memory");
  __builtin_amdgcn_s_barrier();
  __builtin_amdgcn_sched_barrier(0);
}
__device__ __forceinline__ void bar_only() {
  asm volatile("" ::: "memory");
  __builtin_amdgcn_s_barrier();
  __builtin_amdgcn_sched_barrier(0);
}

// ---------------- all weights fp32 -> bf16 (contiguous dst) ----------------
__global__ __launch_bounds__(256) void cvt_all(
    const float* __restrict__ qkv_w, const float* __restrict__ out_w,
    const float* __restrict__ fc1_w, const float* __restrict__ fc2_w,
    const float* __restrict__ outp_w, unsigned short* __restrict__ dst)
{
  int i = blockIdx.x * 256 + threadIdx.x;
  if (i >= 1576960) return;
  const float* src; int off;
  if (i < 786432)       { src = qkv_w;  off = i; }
  else if (i < 1048576) { src = out_w;  off = i - 786432; }
  else if (i < 1310720) { src = fc1_w;  off = i - 1048576; }
  else if (i < 1572864) { src = fc2_w;  off = i - 1310720; }
  else                  { src = outp_w; off = i - 1572864; }
  float4 v = *(const float4*)(src + (size_t)off * 4);
  ushort4 o;
  o.x = f2bf(v.x); o.y = f2bf(v.y); o.z = f2bf(v.z); o.w = f2bf(v.w);
  *(ushort4*)(dst + (size_t)i * 4) = o;
}

// ---------------- conv1d (circular, k=3) + positional embedding -> bf16 ------
__global__ __launch_bounds__(256) void conv_pe_kernel(
    const float* __restrict__ x, const float* __restrict__ cw,
    const float* __restrict__ cb, unsigned short* __restrict__ outb)
{
  const int L = 2048, CIN = 32;
  int b  = blockIdx.x >> 8;
  int l0 = (blockIdx.x & 255) << 3;
  int t  = threadIdx.x;
  __shared__ float xs[10][32];
  for (int idx = t; idx < 320; idx += 256) {
    int rr = idx >> 5, ci = idx & 31;
    int gl = (l0 - 1 + rr + L) & (L - 1);
    xs[rr][ci] = x[((size_t)b * L + gl) * CIN + ci];
  }
  __syncthreads();
  int e0 = t << 1;
  float acc0[8], acc1[8];
  float bb0 = cb[e0], bb1 = cb[e0 + 1];
#pragma unroll
  for (int li = 0; li < 8; li++) { acc0[li] = bb0; acc1[li] = bb1; }
  const float* w0p = cw + (size_t)e0 * 96;
  const float* w1p = w0p + 96;
  for (int ci = 0; ci < 32; ci++) {
#pragma unroll
    for (int kk = 0; kk < 3; kk++) {
      float w0 = w0p[ci * 3 + kk];
      float w1 = w1p[ci * 3 + kk];
#pragma unroll
      for (int li = 0; li < 8; li++) {
        float xv = xs[li + kk][ci];
        acc0[li] += xv * w0;
        acc1[li] += xv * w1;
      }
    }
  }
  float dv = __expf((float)e0 * (-9.210340371976184f / 512.0f));
#pragma unroll
  for (int li = 0; li < 8; li++) {
    int l = l0 + li;
    float arg = (float)l * dv;
    float sv = __sinf(arg), cv = __cosf(arg);   // native v_sin/v_cos path
    size_t off = ((size_t)b * L + l) * 512 + e0;
    ushort2 ob; ob.x = f2bf(acc0[li] + sv); ob.y = f2bf(acc1[li] + cv);
    *(ushort2*)&outb[off] = ob;
  }
}

// ---------------- bf16 MFMA GEMM, 2-phase pipelined, counted vmcnt (T4) ------
// Y[M,N] = X[M,512] @ W[N,512]^T + bias.  Tile 128 x (NFR*32).
// EPI 0: Yb bf16 (QSCALE: cols<512 prescaled).  EPI 1: Yb bf16 = +R(bf16).
// EPI 2: SiLU->Yb.  EPI 3: Yf f32 (no residual).
// VOUT: n-blocks with n0>=1024 write TRANSPOSED into VT[32][64][2048] (V path).
template<int EPI, int QSCALE, int NFR, int VOUT>
__global__ __launch_bounds__(256) void gemm_bf(
    const unsigned short* __restrict__ X,
    const unsigned short* __restrict__ W,
    const float* __restrict__ bias,
    const unsigned short* __restrict__ R,
    unsigned short* __restrict__ Yb,
    float* __restrict__ Yf,
    unsigned short* __restrict__ VT,
    int N)
{
  const int K = 512;
  constexpr int BN = NFR * 32;
  constexpr int WB = NFR * 4096;          // W-region bytes per buffer
  constexpr int BUF = 16384 + WB;
  __shared__ __align__(16) char smem[2 * BUF];
  int t = threadIdx.x;
  int lane = t & 63, wv = t >> 6;
  int g = lane >> 4, li = lane & 15;
  int m0 = (blockIdx.x & 63) << 7;
  int n0 = (blockIdx.x >> 6) * BN;
  int wm = (wv >> 1) << 6;
  int wn = (wv & 1) * (BN / 2);

  int subrow = lane >> 3;
  int coloff = ((lane & 7) ^ subrow) << 3;   // inverse swizzle on global source

  f32x4 acc[4][NFR];
#pragma unroll
  for (int a = 0; a < 4; a++)
#pragma unroll
    for (int b2 = 0; b2 < NFR; b2++) acc[a][b2] = (f32x4){0.f, 0.f, 0.f, 0.f};

  // prologue: stage k-step 0 into buf 0 (no drain: first-iter vmcnt covers it)
#pragma unroll
  for (int j = 0; j < 4; j++) {
    int row = (wv * 4 + j) * 8 + subrow;
    gload16(X + (size_t)(m0 + row) * K + coloff,
            (unsigned short*)(smem + (wv * 4 + j) * 1024));
  }
#pragma unroll
  for (int j = 0; j < NFR; j++) {
    int row = (wv * NFR + j) * 8 + subrow;
    gload16(W + (size_t)(n0 + row) * K + coloff,
            (unsigned short*)(smem + 16384 + (wv * NFR + j) * 1024));
  }

#pragma unroll
  for (int ks = 0; ks < 8; ks++) {
    const int buf = ks & 1;
    char* cur = smem + buf * BUF;
    if (ks < 7) {                     // issue next-tile loads first
      char* nxt = smem + (buf ^ 1) * BUF;
      int k0 = (ks + 1) * 64;
#pragma unroll
      for (int j = 0; j < 4; j++) {
        int row = (wv * 4 + j) * 8 + subrow;
        gload16(X + (size_t)(m0 + row) * K + k0 + coloff,
                (unsigned short*)(nxt + (wv * 4 + j) * 1024));
      }
#pragma unroll
      for (int j = 0; j < NFR; j++) {
        int row = (wv * NFR + j) * 8 + subrow;
        gload16(W + (size_t)(n0 + row) * K + k0 + coloff,
                (unsigned short*)(nxt + 16384 + (wv * NFR + j) * 1024));
      }
      // counted wait: only tile-ks loads (oldest) must land; next tile's stay in flight
      if constexpr (NFR == 4) asm volatile("s_waitcnt vmcnt(8)" ::: "memory");
      else if constexpr (NFR == 2) asm volatile("s_waitcnt vmcnt(6)" ::: "memory");
      else asm volatile("s_waitcnt vmcnt(5)" ::: "memory");
    } else {
      asm volatile("s_waitcnt vmcnt(0)" ::: "memory");
    }
    __builtin_amdgcn_s_barrier();          // all waves' tile-ks data visible
    __builtin_amdgcn_sched_barrier(0);

#pragma unroll
    for (int s = 0; s < 2; s++) {
      bf16x8 af[4], bfr[NFR];
#pragma unroll
      for (int mt = 0; mt < 4; mt++) {
        int row = wm + 16 * mt + li;
        af[mt] = *(const bf16x8*)(cur + (row * 8 + ((g + 4 * s) ^ (row & 7))) * 16);
      }
#pragma unroll
      for (int nt = 0; nt < NFR; nt++) {
        int row = wn + 16 * nt + li;
        bfr[nt] = *(const bf16x8*)(cur + 16384 +
                                   (row * 8 + ((g + 4 * s) ^ (row & 7))) * 16);
      }
#pragma unroll
      for (int mt = 0; mt < 4; mt++)
#pragma unroll
        for (int nt = 0; nt < NFR; nt++)
          acc[mt][nt] = __builtin_amdgcn_mfma_f32_16x16x32_bf16(
              af[mt], bfr[nt], acc[mt][nt], 0, 0, 0);
    }
    if (ks < 7) bar_only();                // guard buffer overwrite by iter ks+1's issues
  }

  float bv[NFR];
#pragma unroll
  for (int nt = 0; nt < NFR; nt++) bv[nt] = bias[n0 + wn + 16 * nt + li];

  if (VOUT && n0 >= 1024) {
    // transposed V output: LDS bounce (rows = tile cols, stride 136 shorts)
    unsigned short* Ts = (unsigned short*)smem;
    __builtin_amdgcn_s_barrier();          // all compute reads of smem done
#pragma unroll
    for (int nt = 0; nt < NFR; nt++) {
      int col = wn + 16 * nt + li;
      float bvn = bv[nt];
#pragma unroll
      for (int mt = 0; mt < 4; mt++) {
        float v0 = acc[mt][nt][0] + bvn, v1 = acc[mt][nt][1] + bvn;
        float v2 = acc[mt][nt][2] + bvn, v3 = acc[mt][nt][3] + bvn;
        uint2 pk;
        asm("v_cvt_pk_bf16_f32 %0, %1, %2" : "=v"(pk.x) : "v"(v0), "v"(v1));
        asm("v_cvt_pk_bf16_f32 %0, %1, %2" : "=v"(pk.y) : "v"(v2), "v"(v3));
        *(uint2*)(Ts + col * 136 + wm + 16 * mt + 4 * g) = pk;
      }
    }
    __syncthreads();
    int vcol = t >> 1, half = t & 1;
    int gc = n0 - 1024 + vcol;
    int bh = (m0 >> 11) * 8 + (gc >> 6);
    int d  = gc & 63;
    unsigned short* dst = VT + ((size_t)bh * 64 + d) * 2048 + (m0 & 2047) + half * 64;
    const unsigned short* srcp = Ts + vcol * 136 + half * 64;
#pragma unroll
    for (int j2 = 0; j2 < 8; j2++)
      *(bf16x8*)(dst + j2 * 8) = *(const bf16x8*)(srcp + j2 * 8);
    return;
  }

#pragma unroll
  for (int mt = 0; mt < 4; mt++) {
#pragma unroll
    for (int i = 0; i < 4; i++) {
      size_t roff = (size_t)(m0 + wm + 16 * mt + 4 * g + i) * N;
#pragma unroll
      for (int nt = 0; nt < NFR; nt++) {
        int col = n0 + wn + 16 * nt + li;
        float v = acc[mt][nt][i] + bv[nt];
        if (EPI == 1) {
          v += bf2f(R[roff + col]);
          Yb[roff + col] = f2bf(v);
        } else if (EPI == 2) {
          v = v / (1.f + __expf(-v));
          Yb[roff + col] = f2bf(v);
        } else if (EPI == 3) {
          Yf[roff + col] = v;
        } else {
          if (QSCALE && col < 512) v *= 0.18033688011112042f;  // 0.125*log2(e)
          Yb[roff + col] = f2bf(v);
        }
      }
    }
  }
}

// ---------------- MFMA flash attention: in-register P, per-chunk schedule ----
// QBLK=128, KVBLK=128; grid 512: bh = bid&31 (XCD-local), qi = bid>>5; 4 waves.
// Q prescaled by 0.125*log2(e); NO-MAX softmax (p = 2^s directly).
// K-row permutation: frag loads K rows 8*(r>>2)+(r&3)+4*odd+32*c so lane holds
// scores for keys 32c+8g+j, q=li == PV A-frag layout; P never touches LDS.
// Per-chunk c: QK(8 mfma) -> exp/pack -> PV(8 mfma) bounds live registers.
// l via ONES-MFMA (r22): accL = mfma(paP, ones, accL) puts rowsum l[q=4g+i]
// exactly at the lane/slot the epilogue needs — deletes the entire cross-lane
// l machinery (32 adds + 2 swizzle + 2 shfl_xor per iter + 8 epilogue shfls).
// r10's version of this failed on VGPR cliff + serial tail; here VGPR has
// grid-capped headroom and the 2 MFMA/chunk weave into the PV cluster.
__global__ __launch_bounds__(256) void attn_mfma(
    const unsigned short* __restrict__ qkv,  // [8192,1536] bf16
    const unsigned short* __restrict__ Vt,   // [32,64,2048] bf16
    unsigned short* __restrict__ ctx)        // [8192,512] bf16
{
  const int L = 2048;
  int bh = blockIdx.x & 31, qi = blockIdx.x >> 5;   // same-bh blocks -> same XCD
  int b = bh >> 3, h = bh & 7;
  int q0 = qi << 7;
  size_t tb = (size_t)b * L;
  int t = threadIdx.x, lane = t & 63, wv = t >> 6;
  int g = lane >> 4, li = lane & 15;
  int lisw7 = li & 7;

  // smem: buf{0,1}: [K 16K | V 16K] at 0/32768  (no P region)
  __shared__ __align__(16) char smem[65536];

  bf16x8 ones;
#pragma unroll
  for (int j = 0; j < 8; j++) ones[j] = (short)0x3F80;   // bf16 1.0

  int wq = q0 + wv * 32;
  bf16x8 qf00, qf01, qf10, qf11;
  {
    const unsigned short* qp0 = qkv + (tb + wq + li) * 1536 + h * 64 + g * 8;
    qf00 = *(const bf16x8*)qp0;
    qf01 = *(const bf16x8*)(qp0 + 32);
    const unsigned short* qp1 = qp0 + (size_t)16 * 1536;
    qf10 = *(const bf16x8*)qp1;
    qf11 = *(const bf16x8*)(qp1 + 32);
  }

  f32x4 accA[4], accB[4], accLA, accLB;
#pragma unroll
  for (int nt = 0; nt < 4; nt++) {
    accA[nt] = (f32x4){0.f, 0.f, 0.f, 0.f};
    accB[nt] = (f32x4){0.f, 0.f, 0.f, 0.f};
  }
  accLA = (f32x4){0.f, 0.f, 0.f, 0.f};
  accLB = (f32x4){0.f, 0.f, 0.f, 0.f};

  // K read offsets: permuted rows, swizzle key (row>>2)&7
  int rowE = ((li >> 2) << 3) + (li & 3);
  int swzE = (li >> 2) << 1;           // (rowE>>2)&7
  int swzO = swzE + 1;                 // ((rowE+4)>>2)&7
  int kE0 = rowE * 128 + ((g ^ swzE) << 4);
  int kE1 = rowE * 128 + (((g + 4) ^ swzE) << 4);
  int kO0 = (rowE + 4) * 128 + ((g ^ swzO) << 4);
  int kO1 = (rowE + 4) * 128 + (((g + 4) ^ swzO) << 4);
  // V fragment offsets (V region rows = 256B, 16 slots): row = 16nt+li, key ^(row&7)
  int vrowb = 16384 + li * 256;
  int vsl[4];
#pragma unroll
  for (int c = 0; c < 4; c++) vsl[c] = ((g + 4 * c) ^ lisw7) << 4;

  // staging pointers: K swizzle key (2j + subrow>>2)&7 ; V swizzle key row&7
  int subrow = lane >> 3;
  const unsigned short* kp[4];
  const unsigned short* vp[4];
#pragma unroll
  for (int j = 0; j < 4; j++) {
    int krow = (wv * 4 + j) * 8 + subrow;
    int swzk = (2 * j + (subrow >> 2)) & 7;
    kp[j] = qkv + (tb + krow) * 1536 + 512 + h * 64 + (((lane & 7) ^ swzk) << 3);
    int vrow = (wv * 4 + j) * 4 + g;
    vp[j] = Vt + ((size_t)bh * 64 + vrow) * 2048 + ((li ^ (vrow & 7)) << 3);
  }

  // prologue: stage tile 0 into buf 0
#pragma unroll
  for (int j = 0; j < 4; j++) {
    gload16(kp[j], (unsigned short*)(smem + (wv * 4 + j) * 1024));
    gload16(vp[j], (unsigned short*)(smem + 16384 + (wv * 4 + j) * 1024));
    kp[j] += (size_t)128 * 1536; vp[j] += 128;
  }
  pipe_sync();

#pragma unroll 2
  for (int it = 0; it < 16; it++) {
    const int buf = it & 1;
    const char* base = smem + buf * 32768;
    if (it < 15) {                    // issue next tile first (latency hides)
      char* nb = smem + (buf ^ 1) * 32768;
#pragma unroll
      for (int j = 0; j < 4; j++) {
        gload16(kp[j], (unsigned short*)(nb + (wv * 4 + j) * 1024));
        gload16(vp[j], (unsigned short*)(nb + 16384 + (wv * 4 + j) * 1024));
        kp[j] += (size_t)128 * 1536; vp[j] += 128;
      }
    }

    const f32x4 kZ = {0.f, 0.f, 0.f, 0.f};
#pragma unroll
    for (int c = 0; c < 4; c++) {
      const char* cb_ = base + c * 4096;
      // QK: 8 MFMA -> this chunk's scores (keys 32c+8g+0..7, q=li)
      bf16x8 k0 = *(const bf16x8*)(cb_ + kE0);
      bf16x8 k1 = *(const bf16x8*)(cb_ + kE1);
      bf16x8 k2 = *(const bf16x8*)(cb_ + kO0);
      bf16x8 k3 = *(const bf16x8*)(cb_ + kO1);
      __builtin_amdgcn_s_setprio(1);
      f32x4 sEA = __builtin_amdgcn_mfma_f32_16x16x32_bf16(k0, qf00, kZ, 0, 0, 0);
      f32x4 sEB = __builtin_amdgcn_mfma_f32_16x16x32_bf16(k0, qf10, kZ, 0, 0, 0);
      f32x4 sOA = __builtin_amdgcn_mfma_f32_16x16x32_bf16(k2, qf00, kZ, 0, 0, 0);
      f32x4 sOB = __builtin_amdgcn_mfma_f32_16x16x32_bf16(k2, qf10, kZ, 0, 0, 0);
      sEA = __builtin_amdgcn_mfma_f32_16x16x32_bf16(k1, qf01, sEA, 0, 0, 0);
      sEB = __builtin_amdgcn_mfma_f32_16x16x32_bf16(k1, qf11, sEB, 0, 0, 0);
      sOA = __builtin_amdgcn_mfma_f32_16x16x32_bf16(k3, qf01, sOA, 0, 0, 0);
      sOB = __builtin_amdgcn_mfma_f32_16x16x32_bf16(k3, qf11, sOB, 0, 0, 0);
      __builtin_amdgcn_s_setprio(0);

      // exp + pack straight into PV A-fragments (registers only)
      bf16x8 paA, paB;
#define EPACK(SE, SO, PA)                                                     \
      {                                                                       \
        float e0 = SE[0], e1 = SE[1], e2 = SE[2], e3 = SE[3];                 \
        float o0 = SO[0], o1 = SO[1], o2 = SO[2], o3 = SO[3];                 \
        asm volatile("v_exp_f32 %0, %0\n\tv_exp_f32 %1, %1\n\t"               \
                     "v_exp_f32 %2, %2\n\tv_exp_f32 %3, %3\n\ts_nop 1"        \
                     : "+v"(e0), "+v"(e1), "+v"(e2), "+v"(e3));               \
        asm volatile("v_exp_f32 %0, %0\n\tv_exp_f32 %1, %1\n\t"               \
                     "v_exp_f32 %2, %2\n\tv_exp_f32 %3, %3\n\ts_nop 1"        \
                     : "+v"(o0), "+v"(o1), "+v"(o2), "+v"(o3));               \
        unsigned int d0, d1, d2, d3;                                          \
        asm("v_cvt_pk_bf16_f32 %0, %1, %2" : "=v"(d0) : "v"(e0), "v"(e1));    \
        asm("v_cvt_pk_bf16_f32 %0, %1, %2" : "=v"(d1) : "v"(e2), "v"(e3));    \
        asm("v_cvt_pk_bf16_f32 %0, %1, %2" : "=v"(d2) : "v"(o0), "v"(o1));    \
        asm("v_cvt_pk_bf16_f32 %0, %1, %2" : "=v"(d3) : "v"(o2), "v"(o3));    \
        unsigned int tmp_[4] = {d0, d1, d2, d3};                              \
        __builtin_memcpy(&PA, tmp_, 16);                                      \
      }
      EPACK(sEA, sOA, paA)
      EPACK(sEB, sOB, paB)
#undef EPACK

      // PV: 8 MFMA for this chunk + 2 l-MFMAs (rowsum via ones B-operand)
      __builtin_amdgcn_s_setprio(1);
#pragma unroll
      for (int nt = 0; nt < 4; nt++) {
        bf16x8 vb = *(const bf16x8*)(base + vrowb + nt * 4096 + vsl[c]);
        accA[nt] = __builtin_amdgcn_mfma_f32_16x16x32_bf16(paA, vb, accA[nt], 0, 0, 0);
        accB[nt] = __builtin_amdgcn_mfma_f32_16x16x32_bf16(paB, vb, accB[nt], 0, 0, 0);
      }
      accLA = __builtin_amdgcn_mfma_f32_16x16x32_bf16(paA, ones, accLA, 0, 0, 0);
      accLB = __builtin_amdgcn_mfma_f32_16x16x32_bf16(paB, ones, accLB, 0, 0, 0);
      __builtin_amdgcn_s_setprio(0);
    }

    pipe_sync();
  }

  // accLA[i] = l for q-row wq+4g+i (col dim redundant); no cross-lane needed.
  float liA[4], liB[4];
#pragma unroll
  for (int i = 0; i < 4; i++) {
    liA[i] = 1.f / accLA[i];
    liB[i] = 1.f / accLB[i];
  }
#pragma unroll
  for (int i = 0; i < 4; i++) {
    size_t ra = (tb + wq + 4 * g + i) * 512 + h * 64;
    size_t rb = (tb + wq + 16 + 4 * g + i) * 512 + h * 64;
#pragma unroll
    for (int nt = 0; nt < 4; nt++) {
      ctx[ra + 16 * nt + li] = f2bf(accA[nt][i] * liA[i]);
      ctx[rb + 16 * nt + li] = f2bf(accB[nt][i] * liB[i]);
    }
  }
}

// ---------------- LayerNorm over E=512 (bf16 in, bf16 out); one wave/row -----
__global__ __launch_bounds__(256) void ln_kernel(
    const unsigned short* __restrict__ X, const float* __restrict__ g,
    const float* __restrict__ b, unsigned short* __restrict__ Yb)
{
  int t = threadIdx.x, lane = t & 63, wv = t >> 6;
  size_t row = (size_t)blockIdx.x * 4 + wv;
  bf16x8 xv = *(const bf16x8*)(X + row * 512 + lane * 8);
  float xf[8];
#pragma unroll
  for (int j = 0; j < 8; j++) xf[j] = bf2f((unsigned short)xv[j]);
  float sum = 0.f, sq = 0.f;
#pragma unroll
  for (int j = 0; j < 8; j++) { sum += xf[j]; sq += xf[j] * xf[j]; }
#pragma unroll
  for (int off = 32; off > 0; off >>= 1) {
    sum += __shfl_xor(sum, off);
    sq  += __shfl_xor(sq, off);
  }
  float mu  = sum * (1.0f / 512.0f);
  float inv = rsqrtf(sq * (1.0f / 512.0f) - mu * mu + 1e-5f);
  float4 g0 = *(const float4*)(g + lane * 8);
  float4 g1 = *(const float4*)(g + lane * 8 + 4);
  float4 b0 = *(const float4*)(b + lane * 8);
  float4 b1 = *(const float4*)(b + lane * 8 + 4);
  float gw[8] = {g0.x, g0.y, g0.z, g0.w, g1.x, g1.y, g1.z, g1.w};
  float bw[8] = {b0.x, b0.y, b0.z, b0.w, b1.x, b1.y, b1.z, b1.w};
  bf16x8 yb;
#pragma unroll
  for (int j = 0; j < 8; j++)
    yb[j] = (short)f2bf((xf[j] - mu) * inv * gw[j] + bw[j]);
  *(bf16x8*)(Yb + row * 512 + lane * 8) = yb;
}

extern "C" void kernel_launch(void* const* d_in, const int* in_sizes, int n_in,
                              void* d_out, int out_size, void* d_ws, size_t ws_size,
                              hipStream_t stream) {
  (void)in_sizes; (void)n_in; (void)out_size; (void)ws_size;
  const float* x      = (const float*)d_in[0];
  const float* conv_w = (const float*)d_in[1];
  const float* conv_b = (const float*)d_in[2];
  const float* qkv_w  = (const float*)d_in[3];
  const float* qkv_b  = (const float*)d_in[4];
  const float* out_w  = (const float*)d_in[5];
  const float* out_b  = (const float*)d_in[6];
  const float* fc1_w  = (const float*)d_in[7];
  const float* fc1_b  = (const float*)d_in[8];
  const float* fc2_w  = (const float*)d_in[9];
  const float* fc2_b  = (const float*)d_in[10];
  const float* ln1_w  = (const float*)d_in[11];
  const float* ln1_b  = (const float*)d_in[12];
  const float* ln2_w  = (const float*)d_in[13];
  const float* ln2_b  = (const float*)d_in[14];
  const float* outp_w = (const float*)d_in[15];
  const float* outp_b = (const float*)d_in[16];
  float* out = (float*)d_out;

  char* p = (char*)d_ws;
  unsigned short* A    = (unsigned short*)p;            p += (size_t)8192 * 512 * 2;
  unsigned short* QKV  = (unsigned short*)p;            p += (size_t)8192 * 1536 * 2;
  unsigned short* VT   = (unsigned short*)p;            p += (size_t)32 * 64 * 2048 * 2;
  unsigned short* CTX  = (unsigned short*)p;            p += (size_t)8192 * 512 * 2;
  unsigned short* Wq   = (unsigned short*)p;            p += (size_t)4 * 1536 * 512 * 2;
  unsigned short* Wo   = (unsigned short*)p;            p += (size_t)4 * 512 * 512 * 2;
  unsigned short* W1   = (unsigned short*)p;            p += (size_t)4 * 512 * 512 * 2;
  unsigned short* W2   = (unsigned short*)p;            p += (size_t)4 * 512 * 512 * 2;
  unsigned short* Wp   = (unsigned short*)p;            p += (size_t)32 * 512 * 2;
  unsigned short* D = QKV;   // aliased: D[8192,512] bf16 in QKV region (disjoint lifetime)

  cvt_all<<<6160, 256, 0, stream>>>(qkv_w, out_w, fc1_w, fc2_w, outp_w, Wq);

  conv_pe_kernel<<<1024, 256, 0, stream>>>(x, conv_w, conv_b, A);

  for (int l = 0; l < 4; l++) {
    gemm_bf<0, 1, 4, 1><<<64 * 12, 256, 0, stream>>>(
        A, Wq + (size_t)l * 1536 * 512, qkv_b + l * 1536, nullptr,
        QKV, nullptr, VT, 1536);
    attn_mfma<<<512, 256, 0, stream>>>(QKV, VT, CTX);
    gemm_bf<1, 0, 2, 0><<<64 * 8, 256, 0, stream>>>(
        CTX, Wo + (size_t)l * 512 * 512, out_b + l * 512, A,
        D, nullptr, nullptr, 512);
    ln_kernel<<<2048, 256, 0, stream>>>(D, ln1_w + l * 512, ln1_b + l * 512, A);
    gemm_bf<2, 0, 2, 0><<<64 * 8, 256, 0, stream>>>(
        A, W1 + (size_t)l * 512 * 512, fc1_b + l * 512, nullptr,
        CTX, nullptr, nullptr, 512);
    gemm_bf<1, 0, 2, 0><<<64 * 8, 256, 0, stream>>>(
        CTX, W2 + (size_t)l * 512 * 512, fc2_b + l * 512, A,
        D, nullptr, nullptr, 512);
    ln_kernel<<<2048, 256, 0, stream>>>(D, ln2_w + l * 512, ln2_b + l * 512, A);
  }
  gemm_bf<3, 0, 1, 0><<<64, 256, 0, stream>>>(
      A, Wp, outp_b, nullptr, nullptr, out, nullptr, 32);
}